// Round 1
// 397.014 us; speedup vs baseline: 1.0022x; 1.0022x over previous
//
#include <hip/hip_runtime.h>

typedef __bf16 bf16;
typedef __bf16 bf16x8 __attribute__((ext_vector_type(8)));
typedef float f32x16 __attribute__((ext_vector_type(16)));

#define B_ROWS 16384
#define N_DIM  4096
#define K_DIM  128

// ---------------------------------------------------------------------------
// Kernel 1: transpose V (4096x128 f32) -> Ut (128x4096 bf16), fused with
// per-column partial sums (for s = V.sum(0)).  (unchanged, proven)
// ---------------------------------------------------------------------------
__global__ __launch_bounds__(256) void prep_kernel(const float* __restrict__ V,
                                                   float* __restrict__ spart,
                                                   bf16* __restrict__ Ut) {
    __shared__ bf16 tile[128 * 136];
    __shared__ float sp[256];
    const int t = threadIdx.x;
    const int jbase = blockIdx.x * 128;
    const int c  = t & 127;
    const int j0 = t >> 7;

    float sacc = 0.f;
#pragma unroll 8
    for (int i = 0; i < 64; ++i) {
        int j = j0 + 2 * i;
        float v = V[(size_t)(jbase + j) * K_DIM + c];
        sacc += v;
        tile[c * 136 + j] = (bf16)v;
    }
    sp[t] = sacc;
    __syncthreads();
    if (t < 128) spart[blockIdx.x * 128 + t] = sp[t] + sp[t + 128];

    const int col = t >> 1, half = t & 1;
#pragma unroll
    for (int i = 0; i < 4; ++i) {
        uint4 d = *(const uint4*)&tile[col * 136 + half * 64 + i * 16];
        *(uint4*)&Ut[(size_t)col * N_DIM + jbase + half * 64 + i * 16] = d;
    }
}

// ---------------------------------------------------------------------------
// Kernel 2 (main): BM=32 rows/block, 512 blocks, 256 threads = 4 waves.
// T3/T4 counted-wait loop: raw s_barrier + lgkmcnt(0) for xs visibility;
// vmcnt(12) (never 0) before MFMA so next-tile DMA + 2-deep x reg prefetch
// stay in flight across the barrier. us rows are wave-private so per-wave
// vmcnt ordering is sufficient for the DMA->ds_read dependency.
// Per-iter vmcnt queue (oldest->newest) at the wait point:
//   [DMA tile i (4)] [regs tile i+1 (4)] [DMA tile i+1 (4)] [regs tile i+2 (4)]
// vmcnt(12) retires exactly the DMA for the buffer we are about to read.
// snorm = ||V.sum(0)||^2 folded into epilogue (finalize_s kernel removed).
// ---------------------------------------------------------------------------
__global__ __launch_bounds__(256, 2) void fm_main(const float* __restrict__ x,
                                                  const float* __restrict__ W,
                                                  const float* __restrict__ bptr,
                                                  const bf16* __restrict__ Ut,
                                                  const float* __restrict__ spart,
                                                  float* __restrict__ out) {
    __shared__ bf16  xs[2][32 * 72];      // padded (+8) x tile, bf16
    __shared__ bf16  us[2][128 * 64];     // unpadded Ut tile (global_load_lds dest)
    __shared__ float redxs[256];
    __shared__ float redxw[256];
    __shared__ float rowsq[4 * 32];
    __shared__ float snred[2];

    const int t    = threadIdx.x;
    const int wave = t >> 6;
    const int lane = t & 63;
    const int l31  = lane & 31;
    const int h    = lane >> 5;
    const int r0   = blockIdx.x * 32;

    const int srow = t >> 3;              // 0..31 x row
    const int scg  = t & 7;               // 0..7 chunk of 8 floats

    f32x16 acc;
#pragma unroll
    for (int i = 0; i < 16; ++i) acc[i] = 0.f;

    float xsum_acc = 0.f, xw_acc = 0.f;
    const float* xrow = x + (size_t)(r0 + srow) * N_DIM + scg * 8;
    const float* wrow = W + scg * 8;
    // DMA source: lane covers (col_local = lane>>3, kchunk = lane&7)
    const bf16* ub = Ut + (size_t)(wave * 32 + (lane >> 3)) * N_DIM + (lane & 7) * 8;

    // ---- prologue: DMA tile 0; register tiles 0 and 1 ----
#pragma unroll
    for (int j = 0; j < 4; ++j) {
        __builtin_amdgcn_global_load_lds(
            (const __attribute__((address_space(1))) void*)(ub + (size_t)j * 8 * N_DIM),
            (__attribute__((address_space(3))) void*)&us[0][(wave * 32 + j * 8) * 64],
            16, 0, 0);
    }
    float4 a0 = *(const float4*)(xrow);
    float4 a1 = *(const float4*)(xrow + 4);
    float4 w0 = *(const float4*)(wrow);
    float4 w1 = *(const float4*)(wrow + 4);
    float4 b0 = *(const float4*)(xrow + 64);
    float4 b1 = *(const float4*)(xrow + 68);
    float4 v0 = *(const float4*)(wrow + 64);
    float4 v1 = *(const float4*)(wrow + 68);

    for (int it = 0; it < 64; ++it) {
        const int bsel = it & 1;
        const int kb1 = (it < 63) ? (it + 1) * 64 : 0;  // clamp: harmless reload
        const int kb2 = (it < 62) ? (it + 2) * 64 : 0;

        // ---- store x regs (tile it) into xs[bsel] ----
        bf16x8 xb;
        xb[0] = (bf16)a0.x; xb[1] = (bf16)a0.y; xb[2] = (bf16)a0.z; xb[3] = (bf16)a0.w;
        xb[4] = (bf16)a1.x; xb[5] = (bf16)a1.y; xb[6] = (bf16)a1.z; xb[7] = (bf16)a1.w;
        *(bf16x8*)&xs[bsel][srow * 72 + scg * 8] = xb;

        // xs[bsel] visible to all waves; no vmcnt drain here (counted wait below)
        asm volatile("s_waitcnt lgkmcnt(0)" ::: "memory");
        __builtin_amdgcn_s_barrier();
        __builtin_amdgcn_sched_barrier(0);

        // ---- issue DMA tile it+1 -> us[bsel^1] (oldest in vmcnt queue) ----
#pragma unroll
        for (int j = 0; j < 4; ++j) {
            __builtin_amdgcn_global_load_lds(
                (const __attribute__((address_space(1))) void*)(ub + (size_t)j * 8 * N_DIM + kb1),
                (__attribute__((address_space(3))) void*)&us[bsel ^ 1][(wave * 32 + j * 8) * 64],
                16, 0, 0);
        }
        __builtin_amdgcn_sched_barrier(0);   // pin DMA-before-loads issue order

        // ---- 2-deep register prefetch: tile it+2 ----
        float4 n0 = *(const float4*)(xrow + kb2);
        float4 n1 = *(const float4*)(xrow + kb2 + 4);
        float4 m0 = *(const float4*)(wrow + kb2);
        float4 m1 = *(const float4*)(wrow + kb2 + 4);

        // ---- exact fp32 side computations on tile-it regs ----
        xsum_acc += (a0.x + a0.y + a0.z + a0.w) + (a1.x + a1.y + a1.z + a1.w);
        xw_acc   += a0.x * w0.x + a0.y * w0.y + a0.z * w0.z + a0.w * w0.w
                  + a1.x * w1.x + a1.y * w1.y + a1.z * w1.z + a1.w * w1.w;

        // retire exactly the us[bsel] DMA (12 newer VMEM ops stay in flight)
        asm volatile("s_waitcnt vmcnt(12)" ::: "memory");
        __builtin_amdgcn_sched_barrier(0);

        // ---- MFMA on buffer bsel ----
        __builtin_amdgcn_s_setprio(1);
#pragma unroll
        for (int ks = 0; ks < 64; ks += 16) {
            bf16x8 af  = *(const bf16x8*)&xs[bsel][l31 * 72 + ks + h * 8];
            bf16x8 bfv = *(const bf16x8*)&us[bsel][(wave * 32 + l31) * 64 + ks + h * 8];
            acc = __builtin_amdgcn_mfma_f32_32x32x16_bf16(af, bfv, acc, 0, 0, 0);
        }
        __builtin_amdgcn_s_setprio(0);

        a0 = b0; a1 = b1; w0 = v0; w1 = v1;
        b0 = n0; b1 = n1; v0 = m0; v1 = m1;
    }

    // ---- epilogue ----
    redxs[t] = xsum_acc;
    redxw[t] = xw_acc;

    // per-row sum of squares over this wave's 32 cols.
    // C/D layout: col = lane&31, row = (reg&3) + 8*(reg>>2) + 4*(lane>>5)
#pragma unroll
    for (int r = 0; r < 16; ++r) {
        float s = acc[r] * acc[r];
        s += __shfl_xor(s, 1);
        s += __shfl_xor(s, 2);
        s += __shfl_xor(s, 4);
        s += __shfl_xor(s, 8);
        s += __shfl_xor(s, 16);
        if (l31 == 0) {
            int row = (r & 3) + 8 * (r >> 2) + 4 * h;
            rowsq[wave * 32 + row] = s;
        }
    }

    // snorm = ||V.sum(0)||^2 from spart (32x128, L2-resident), waves 0-1.
    // Same reduction order as the removed finalize_s kernel.
    if (t < 128) {
        float sv = 0.f;
#pragma unroll
        for (int bb = 0; bb < 32; ++bb) sv += spart[bb * 128 + t];
        float sq = sv * sv;
#pragma unroll
        for (int m = 32; m >= 1; m >>= 1) sq += __shfl_down(sq, m, 64);
        if ((t & 63) == 0) snred[t >> 6] = sq;
    }
    __syncthreads();   // also drains the dangling tail prefetch VMEM ops

    if (t < 32) {
        float xsum = 0.f, xw = 0.f;
#pragma unroll
        for (int g = 0; g < 8; ++g) { xsum += redxs[t * 8 + g]; xw += redxw[t * 8 + g]; }
        float sq = rowsq[t] + rowsq[32 + t] + rowsq[64 + t] + rowsq[96 + t];
        float snorm = snred[0] + snred[1];
        float bv = bptr[0];
        out[r0 + t] = bv + xw + 0.5f * sq - 0.5f * xsum * xsum * snorm;
    }
}

// ---------------------------------------------------------------------------
extern "C" void kernel_launch(void* const* d_in, const int* in_sizes, int n_in,
                              void* d_out, int out_size, void* d_ws, size_t ws_size,
                              hipStream_t stream) {
    const float* x  = (const float*)d_in[0];
    const float* W  = (const float*)d_in[1];
    const float* bp = (const float*)d_in[2];
    const float* V  = (const float*)d_in[3];
    float* out = (float*)d_out;

    char* ws = (char*)d_ws;
    float* spart = (float*)(ws + 1024);        // 16 KB
    bf16*  Ut    = (bf16*)(ws + 32768);        // 1 MB

    hipLaunchKernelGGL(prep_kernel, dim3(32), dim3(256), 0, stream, V, spart, Ut);
    hipLaunchKernelGGL(fm_main, dim3(512), dim3(256), 0, stream, x, W, bp, Ut, spart, out);
}